// Round 1
// baseline (84.035 us; speedup 1.0000x reference)
//
#include <hip/hip_runtime.h>
#include <hip/hip_bf16.h>
#include <math.h>

// WeightedCoxNLL on MI355X.
//
// loss = -(1/n) * sum_{i != lexmax} cens_i * (h_i - log(S_i) + log(t_i))
//   S_i = sum over j with (t_j, j) >lex (t_i, i) of s_j,  s_j = t_j * exp(h_j)
//   cens_i = (t_i < 2) & event_i ;  n = sum_i cens_i
// This reproduces jnp.argsort's stable ordering exactly (lexicographic tie-break)
// without sorting: O(N^2) pairwise, N=16384 -> 2.7e8 cheap ops, data L2-resident.

namespace {
constexpr int N       = 16384;
constexpr int BLK     = 256;
constexpr int CHUNKS  = 8;
constexpr int CHUNK   = N / CHUNKS;   // 2048 j's per pair-block
constexpr int IBLOCKS = N / BLK;      // 64 i-blocks
}

// ---- ws layout (bytes) ----
// [0,       131072)  float2 ts[N]              (t_i, s_i)
// [131072,  655360)  float  Spart[CHUNKS][N]
// [655360,  655368)  float  acc[2]             {sum_terms, n_events}
// [655368,  655372)  uint   flag               (1 = event_status is byte bools)
// [655372,  655376)  uint   done_ctr

__global__ __launch_bounds__(BLK)
void cox_prep(const float* __restrict__ pred, const float* __restrict__ ytime,
              const unsigned int* __restrict__ ev_words,
              float2* __restrict__ ts, float* __restrict__ acc,
              unsigned int* __restrict__ flag, unsigned int* __restrict__ done_ctr) {
  int i = blockIdx.x * BLK + threadIdx.x;
  float t = ytime[i];
  float h = pred[i];
  ts[i] = make_float2(t, t * expf(h));

  if (blockIdx.x == 0) {
    // Layout detection: read first 16384 bytes (safe whether the buffer is
    // 16384 bool bytes or 16384 int32 words). If event_status were int32
    // 0/1 values, every byte at offset %4 != 0 is zero. If it is packed
    // bool bytes, ~3/4 of the actual 0/1 flags sit at those offsets.
    unsigned int v = 0;
    for (int k = threadIdx.x; k < N / 4; k += BLK)
      v |= ev_words[k] & 0xFFFFFF00u;
    unsigned long long any = __ballot(v != 0u);
    __shared__ unsigned int sh[BLK / 64];
    if ((threadIdx.x & 63) == 0) sh[threadIdx.x >> 6] = (any != 0ull) ? 1u : 0u;
    __syncthreads();
    if (threadIdx.x == 0) {
      *flag = sh[0] | sh[1] | sh[2] | sh[3];
      acc[0] = 0.f;
      acc[1] = 0.f;
      *done_ctr = 0u;
    }
  }
}

__global__ __launch_bounds__(BLK)
void cox_pair(const float2* __restrict__ ts, float* __restrict__ Spart) {
  __shared__ float2 tile[CHUNK];            // 16 KB
  const int bi = blockIdx.x & (IBLOCKS - 1);
  const int c  = blockIdx.x >> 6;           // IBLOCKS == 64
  const int i  = bi * BLK + (int)threadIdx.x;
  const int jbase = c * CHUNK;

  const float2 me = ts[i];

  for (int k = threadIdx.x; k < CHUNK; k += BLK)
    tile[k] = ts[jbase + k];
  __syncthreads();

  float S = 0.f;
#pragma unroll 8
  for (int j = 0; j < CHUNK; ++j) {
    float2 v = tile[j];                     // broadcast LDS read, conflict-free
    bool succ = (v.x > me.x) | ((v.x == me.x) & ((jbase + j) > i));
    S += succ ? v.y : 0.f;
  }
  Spart[c * N + i] = S;
}

__global__ __launch_bounds__(BLK)
void cox_combine(const float* __restrict__ pred, const float* __restrict__ ytime,
                 const void* __restrict__ ev, const float* __restrict__ Spart,
                 float* __restrict__ acc, const unsigned int* __restrict__ flag,
                 unsigned int* __restrict__ done_ctr, float* __restrict__ out) {
  const int i = blockIdx.x * BLK + (int)threadIdx.x;

  float S = 0.f;
#pragma unroll
  for (int c = 0; c < CHUNKS; ++c) S += Spart[c * N + i];

  float t = ytime[i];
  float h = pred[i];
  bool e;
  if (*flag) e = ((const unsigned char*)ev)[i] != 0;
  else       e = ((const int*)ev)[i] != 0;

  bool cens = (t < 2.0f) & e;
  // S > 0 excludes exactly the lexicographic-max element (reference's [:-1]).
  float term  = (cens && (S > 0.f)) ? (h - logf(S) + logf(t)) : 0.f;
  float nterm = cens ? 1.f : 0.f;

#pragma unroll
  for (int off = 32; off > 0; off >>= 1) {
    term  += __shfl_down(term, off, 64);
    nterm += __shfl_down(nterm, off, 64);
  }
  if ((threadIdx.x & 63) == 0) {
    atomicAdd(&acc[0], term);
    atomicAdd(&acc[1], nterm);
  }

  __threadfence();
  __syncthreads();
  if (threadIdx.x == 0) {
    unsigned int prev = atomicAdd(done_ctr, 1u);
    if (prev == gridDim.x - 1) {
      float s0 = atomicAdd(&acc[0], 0.f);   // coherent (L2) reads
      float s1 = atomicAdd(&acc[1], 0.f);
      out[0] = -s0 / s1;
    }
  }
}

extern "C" void kernel_launch(void* const* d_in, const int* in_sizes, int n_in,
                              void* d_out, int out_size, void* d_ws, size_t ws_size,
                              hipStream_t stream) {
  const float* pred  = (const float*)d_in[0];
  const float* ytime = (const float*)d_in[1];
  const void*  ev    = d_in[2];
  float* out = (float*)d_out;

  char* ws = (char*)d_ws;
  float2*       ts    = (float2*)ws;                                   // 128 KB
  float*        Spart = (float*)(ws + (size_t)N * sizeof(float2));     // 512 KB
  float*        acc   = (float*)(ws + 655360);
  unsigned int* flag  = (unsigned int*)(ws + 655368);
  unsigned int* dctr  = (unsigned int*)(ws + 655372);

  cox_prep<<<N / BLK, BLK, 0, stream>>>(pred, ytime, (const unsigned int*)ev,
                                        ts, acc, flag, dctr);
  cox_pair<<<IBLOCKS * CHUNKS, BLK, 0, stream>>>(ts, Spart);
  cox_combine<<<N / BLK, BLK, 0, stream>>>(pred, ytime, ev, Spart,
                                           acc, flag, dctr, out);
}